// Round 10
// baseline (3330.780 us; speedup 1.0000x reference)
//
#include <hip/hip_runtime.h>
#include <math.h>

typedef _Float16 half8 __attribute__((ext_vector_type(8)));
typedef _Float16 half4 __attribute__((ext_vector_type(4)));
typedef float float4v __attribute__((ext_vector_type(4)));

constexpr int Lc   = 2048;  // L_IN
constexpr int DECc = 64;    // DEC_LEN
constexpr int Hc   = 128;   // H
constexpr int EMBc = 16;    // EMB
constexpr int INc  = 18;    // IN_SIZE
constexpr int NBc  = 2;     // batches per block (R10: 4->2, grid 512 => 2 blocks/CU, indep barriers)
constexpr int NTc  = 512;   // 8 waves
constexpr int KT   = 5;     // k-tiles of 32 (z padded to 160)
constexpr int CARD = 200;
constexpr int GS2  = 528;   // g16 per-batch stride in halves

__device__ __forceinline__ float rcp_(float x) { return __builtin_amdgcn_rcpf(x); }
__device__ __forceinline__ float sigm(float x) { return rcp_(1.0f + __expf(-x)); }
__device__ __forceinline__ float tanh_(float x) { return 2.0f * rcp_(1.0f + __expf(-2.0f * x)) - 1.0f; }
__device__ __forceinline__ float softplus_(float x) { return __logf(1.0f + __expf(x)); }

// z LDS layout = B-fragment order for mfma_f32_16x16x32_f16 (verified R4-R9):
// frag kt: lane l holds halves [l*8..l*8+8) = B[k = kt*32 + (l>>4)*8 + j][n = l&15]
__device__ __forceinline__ int zslot(int k, int b) {
    return (k >> 5) * 512 + (b + 16 * ((k & 31) >> 3)) * 8 + (k & 7);
}

__global__ __launch_bounds__(NTc, 1) void rnnar_kernel(
    const int*   __restrict__ cat_in,  const float* __restrict__ cont_in,
    const float* __restrict__ X_in,    const int*   __restrict__ cat_out,
    const float* __restrict__ cont_out,const float* __restrict__ emb_table,
    const float* __restrict__ cont_w,
    const float* __restrict__ Wih_e, const float* __restrict__ Whh_e, const float* __restrict__ b_e,
    const float* __restrict__ Wih_d, const float* __restrict__ Whh_d, const float* __restrict__ b_d,
    const float* __restrict__ Wm, const float* __restrict__ bm,
    const float* __restrict__ Ws, const float* __restrict__ bs,
    const float* __restrict__ Wv, const float* __restrict__ bv,
    float* __restrict__ out)
{
    // total static LDS ~38.7 KB  (2 blocks/CU => 77 KB < 160 KB)
    __shared__ _Float16      z_lds[KT * 512];      // 5 KB   B-frags
    __shared__ _Float16      g16[NBc * GS2];       // 2.1 KB gate pre-activations (f16)
    __shared__ _Float16      emb_lds[CARD * EMBc]; // 6.4 KB embedding table (f16)
    __shared__ _Float16      xs0[NBc * Lc];        // 8 KB   cont_in * w00  (f16)
    __shared__ _Float16      xs1[NBc * Lc];        // 8 KB   X_in          (f16)
    __shared__ _Float16      xo_lds[NBc * DECc];   // 256 B  cont_out * w00
    __shared__ unsigned char catb[NBc * Lc];       // 4 KB   cat_in  (CARD<256)
    __shared__ unsigned char catob[NBc * DECc];    // 128 B  cat_out
    __shared__ float         h32_lds[NBc * 132];   // 1 KB   fp32 h for heads
    __shared__ float         wh_lds[6 * Hc];       // 3 KB   head weights
    __shared__ float         hb_lds[8];            // head biases

    const int tid  = threadIdx.x;
    const int lane = tid & 63;
    const int wv   = tid >> 6;        // wave 0..7
    const int quad = lane >> 4;       // 0..3
    const int col  = lane & 15;       // C-col (= batch)
    const int b0   = blockIdx.x * NBc;
    const float w00 = cont_w[0];

    const int xk = tid / NBc, xb = tid % NBc;       // x-writer role (tid < INc*NBc)
    const int m = tid & (Hc - 1), pb = tid >> 7;    // phase-2 role (tid < Hc*NBc)
    const int cell_base = 16 * wv + quad * 4;

    // ---------------- staging: everything into LDS once ----------------
    {
        int* z32 = (int*)z_lds;
        for (int i = tid; i < KT * 256; i += NTc) z32[i] = 0;
    }
    for (int i = tid; i < NBc * Lc; i += NTc) {
        const int b = i >> 11, t = i & (Lc - 1);
        catb[i] = (unsigned char)cat_in[(b0 + b) * Lc + t];
        xs0[i]  = (_Float16)(cont_in[(b0 + b) * Lc + t] * w00);
        xs1[i]  = (_Float16)(X_in[(b0 + b) * Lc + t]);
    }
    if (tid < NBc * DECc) {
        const int b = tid >> 6, t = tid & 63;
        catob[tid]  = (unsigned char)cat_out[(b0 + b) * DECc + t];
        xo_lds[tid] = (_Float16)(cont_out[(b0 + b) * DECc + t] * w00);
    }
    for (int i = tid; i < CARD * EMBc; i += NTc) emb_lds[i] = (_Float16)emb_table[i];
    for (int i = tid; i < 6 * Hc; i += NTc) {
        const int o = i >> 7, k = i & 127;
        wh_lds[i] = (o == 0) ? Wm[k] : (o == 1) ? Ws[k] : Wv[(o - 2) * Hc + k];
    }
    if (tid == 0) { hb_lds[0] = bm[0]; hb_lds[1] = bs[0]; }
    if (tid < 4)  { hb_lds[2 + tid] = bv[tid]; }

    // ---- A-fragments: wave wv owns row-tiles {wv + 8i} = gate i, cells 16wv..16wv+15 ----
    half8 Af[4][KT];
    float4v bias4[4];
    #define LOAD_AB(WIH, WHH, BB)                                              \
    {                                                                          \
        _Pragma("unroll")                                                      \
        for (int i = 0; i < 4; ++i) {                                          \
            const int row = 128 * i + 16 * wv + col;                           \
            _Pragma("unroll")                                                  \
            for (int kt = 0; kt < KT; ++kt) {                                  \
                half8 f;                                                       \
                _Pragma("unroll")                                              \
                for (int j = 0; j < 8; ++j) {                                  \
                    const int k = 32 * kt + quad * 8 + j;                      \
                    float v = 0.0f;                                            \
                    if (k < INc)            v = WIH[row * INc + k];            \
                    else if (k < INc + Hc)  v = WHH[row * Hc + (k - INc)];     \
                    f[j] = (_Float16)v;                                        \
                }                                                              \
                Af[i][kt] = f;                                                 \
            }                                                                  \
            float4v bb;                                                        \
            _Pragma("unroll")                                                  \
            for (int r = 0; r < 4; ++r) bb[r] = BB[128 * i + cell_base + r];   \
            bias4[i] = bb;                                                     \
        }                                                                      \
    }

    LOAD_AB(Wih_e, Whh_e, b_e);

    __syncthreads();   // staging visible

    // x(0) into z (h part already zero)
    if (tid < INc * NBc) {
        _Float16 v;
        if (xk < EMBc)       v = emb_lds[(int)catb[xb * Lc] * EMBc + xk];
        else if (xk == EMBc) v = xs0[xb * Lc];
        else                 v = xs1[xb * Lc];
        z_lds[zslot(xk, xb)] = v;
    }
    __syncthreads();

    float c_reg = 0.f;
    const _Float16* zp = z_lds + lane * 8;

    // ===================== encoder =====================
    for (int t = 0; t < Lc; ++t) {
        // phase 1: MFMA gates, result -> g16 (f16)
        half8 bf[KT];
        #pragma unroll
        for (int kt = 0; kt < KT; ++kt) bf[kt] = *(const half8*)(zp + kt * 512);
        #pragma unroll
        for (int i = 0; i < 4; ++i) {
            float4v a = bias4[i];
            #pragma unroll
            for (int kt = 0; kt < KT; ++kt)
                a = __builtin_amdgcn_mfma_f32_16x16x32_f16(Af[i][kt], bf[kt], a, 0, 0, 0);
            if (col < NBc) {
                half4 hv;
                #pragma unroll
                for (int r = 0; r < 4; ++r) hv[r] = (_Float16)a[r];
                *(half4*)(g16 + col * GS2 + 128 * i + cell_base) = hv;
            }
        }
        __syncthreads();

        // phase 2: one cell-update per thread (cell m, batch pb) — all-LDS inputs
        if (tid < Hc * NBc) {
            const float gi = (float)g16[pb * GS2 + m];
            const float gf = (float)g16[pb * GS2 + 128 + m];
            const float gg = (float)g16[pb * GS2 + 256 + m];
            const float go = (float)g16[pb * GS2 + 384 + m];
            const float cn = sigm(gf) * c_reg + sigm(gi) * tanh_(gg);
            c_reg = cn;
            z_lds[zslot(INc + m, pb)] = (_Float16)(sigm(go) * tanh_(cn));
        }
        // x(t+1) from LDS (clamped: t=Lc-1 re-writes x(Lc-1) = decoder-init x)
        if (tid < INc * NBc) {
            const int t1 = (t + 1 < Lc) ? t + 1 : Lc - 1;
            _Float16 v;
            if (xk < EMBc)       v = emb_lds[(int)catb[xb * Lc + t1] * EMBc + xk];
            else if (xk == EMBc) v = xs0[xb * Lc + t1];
            else                 v = xs1[xb * Lc + t1];
            z_lds[zslot(xk, xb)] = v;
        }
        __syncthreads();
    }

    // ===================== decoder =====================
    LOAD_AB(Wih_d, Whh_d, b_d);
    const float bm0 = hb_lds[0], bs0 = hb_lds[1];

    for (int t = 0; t < DECc; ++t) {
        half8 bf[KT];
        #pragma unroll
        for (int kt = 0; kt < KT; ++kt) bf[kt] = *(const half8*)(zp + kt * 512);
        #pragma unroll
        for (int i = 0; i < 4; ++i) {
            float4v a = bias4[i];
            #pragma unroll
            for (int kt = 0; kt < KT; ++kt)
                a = __builtin_amdgcn_mfma_f32_16x16x32_f16(Af[i][kt], bf[kt], a, 0, 0, 0);
            if (col < NBc) {
                half4 hv;
                #pragma unroll
                for (int r = 0; r < 4; ++r) hv[r] = (_Float16)a[r];
                *(half4*)(g16 + col * GS2 + 128 * i + cell_base) = hv;
            }
        }
        __syncthreads();

        // phase 2
        if (tid < Hc * NBc) {
            const float gi = (float)g16[pb * GS2 + m];
            const float gf = (float)g16[pb * GS2 + 128 + m];
            const float gg = (float)g16[pb * GS2 + 256 + m];
            const float go = (float)g16[pb * GS2 + 384 + m];
            const float cn = sigm(gf) * c_reg + sigm(gi) * tanh_(gg);
            c_reg = cn;
            const float hv = sigm(go) * tanh_(cn);
            z_lds[zslot(INc + m, pb)] = (_Float16)hv;
            h32_lds[pb * 132 + m] = hv;
        }
        // feats_out(t) -> x(t+1); slot 17 (mu) written by heads below
        if (tid < INc * NBc && xk < INc - 1) {
            _Float16 v;
            if (xk < EMBc) v = emb_lds[(int)catob[xb * DECc + t] * EMBc + xk];
            else           v = xo_lds[xb * DECc + t];
            z_lds[zslot(xk, xb)] = v;
        }
        __syncthreads();

        // phase 3: heads (mu, std, v[0..3]) per batch — pure LDS inputs
        if (tid < NBc * 8) {
            const int b = tid >> 3, o = tid & 7;
            if (o < 6) {
                float s = 0.0f;
                #pragma unroll 8
                for (int k = 0; k < Hc; ++k) s += wh_lds[o * Hc + k] * h32_lds[b * 132 + k];
                const int gb = b0 + b;
                if (o == 0) {
                    const float mu = s + bm0;
                    out[gb * DECc + t] = mu;
                    z_lds[zslot(INc - 1, b)] = (_Float16)mu;   // mu feedback
                } else if (o == 1) {
                    out[65536 + gb * DECc + t] = softplus_(s + bs0);
                } else {
                    out[131072 + (gb * DECc + t) * 4 + (o - 2)] = s + hb_lds[2 + (o - 2)];
                }
            }
        }
        __syncthreads();
    }
    #undef LOAD_AB
}

extern "C" void kernel_launch(void* const* d_in, const int* in_sizes, int n_in,
                              void* d_out, int out_size, void* d_ws, size_t ws_size,
                              hipStream_t stream) {
    rnnar_kernel<<<1024 / NBc, NTc, 0, stream>>>(
        (const int*)d_in[0],   (const float*)d_in[1],  (const float*)d_in[2],
        (const int*)d_in[3],   (const float*)d_in[4],  (const float*)d_in[5],
        (const float*)d_in[6],
        (const float*)d_in[7], (const float*)d_in[8],  (const float*)d_in[9],
        (const float*)d_in[10],(const float*)d_in[11], (const float*)d_in[12],
        (const float*)d_in[13],(const float*)d_in[14],
        (const float*)d_in[15],(const float*)d_in[16],
        (const float*)d_in[17],(const float*)d_in[18],
        (float*)d_out);
}

// Round 11
// 1453.504 us; speedup vs baseline: 2.2916x; 2.2916x over previous
//
#include <hip/hip_runtime.h>
#include <math.h>

typedef _Float16 half8 __attribute__((ext_vector_type(8)));
typedef _Float16 half4 __attribute__((ext_vector_type(4)));
typedef float float4v __attribute__((ext_vector_type(4)));

constexpr int Lc   = 2048;  // L_IN
constexpr int DECc = 64;    // DEC_LEN
constexpr int Hc   = 128;   // H
constexpr int EMBc = 16;    // EMB
constexpr int INc  = 18;    // IN_SIZE
constexpr int NBc  = 4;     // batches per block
constexpr int NTc  = 512;   // 8 waves
constexpr int KT   = 5;     // k-tiles of 32 (z padded to 160)
constexpr int CARD = 200;
constexpr int ZS   = 160;   // z stride per batch (halves)

__device__ __forceinline__ float rcp_(float x) { return __builtin_amdgcn_rcpf(x); }
__device__ __forceinline__ float sigm(float x) { return rcp_(1.0f + __expf(-x)); }
__device__ __forceinline__ float tanh_(float x) { return 2.0f * rcp_(1.0f + __expf(-2.0f * x)) - 1.0f; }
__device__ __forceinline__ float softplus_(float x) { return __logf(1.0f + __expf(x)); }

// Transposed GEMM: D[m=batch][n=gate] = z[m][k] * Wc^T[k][n], gate order g=4*cell+gt.
// A-frag (z): lane holds A[m=col][k=quad*8+j]  (batches replicated col&3)
// B-frag (W^T): lane holds B[k=kt*32+quad*8+j][n=16*tile+col]
// C: col = n (gate within tile), reg r = batch (rows replicated mod 4)

__global__ __launch_bounds__(NTc, 1) void rnnar_kernel(
    const int*   __restrict__ cat_in,  const float* __restrict__ cont_in,
    const float* __restrict__ X_in,    const int*   __restrict__ cat_out,
    const float* __restrict__ cont_out,const float* __restrict__ emb_table,
    const float* __restrict__ cont_w,
    const float* __restrict__ Wih_e, const float* __restrict__ Whh_e, const float* __restrict__ b_e,
    const float* __restrict__ Wih_d, const float* __restrict__ Whh_d, const float* __restrict__ b_d,
    const float* __restrict__ Wm, const float* __restrict__ bm,
    const float* __restrict__ Ws, const float* __restrict__ bs,
    const float* __restrict__ Wv, const float* __restrict__ bv,
    float* __restrict__ out)
{
    // ~59 KB total
    __shared__ _Float16      z_lds[2][NBc * ZS];   // 2.5 KB double-buffered z, [b][k]
    __shared__ _Float16      sc[8 * 256];          // 4 KB  per-wave gate shuffle scratch
    __shared__ _Float16      emb_lds[CARD * EMBc]; // 6.4 KB
    __shared__ _Float16      xs0[NBc * Lc];        // 16 KB cont_in * w00
    __shared__ _Float16      xs1[NBc * Lc];        // 16 KB X_in
    __shared__ _Float16      xo_lds[NBc * DECc];   // 512 B cont_out * w00
    __shared__ unsigned char catb[NBc * Lc];       // 8 KB
    __shared__ unsigned char catob[NBc * DECc];    // 256 B
    __shared__ float         h32_lds[NBc * 132];   // 2.1 KB
    __shared__ float         wh_lds[6 * Hc];       // 3 KB
    __shared__ float         hb_lds[8];

    const int tid  = threadIdx.x;
    const int lane = tid & 63;
    const int wv   = tid >> 6;        // wave 0..7
    const int q    = lane >> 4;       // quad 0..3
    const int col  = lane & 15;
    const int b0   = blockIdx.x * NBc;
    const float w00 = cont_w[0];

    const int xk = tid >> 2, xb = tid & 3;   // x-writer role (tid < 72)
    const int cl = lane >> 2;                // activation role: cell-local 0..15
    const int ab = lane & 3;                 //                  batch 0..3
    const int cell = 16 * wv + cl;           // this lane's cell (c_reg owner)

    // ---------------- staging ----------------
    {
        int* z32 = (int*)&z_lds[0][0];
        for (int i = tid; i < NBc * ZS; i += NTc) z32[i] = 0;  // both buffers (2*NBc*ZS halves)
    }
    for (int i = tid; i < NBc * Lc; i += NTc) {
        const int b = i >> 11, t = i & (Lc - 1);
        catb[i] = (unsigned char)cat_in[(b0 + b) * Lc + t];
        xs0[i]  = (_Float16)(cont_in[(b0 + b) * Lc + t] * w00);
        xs1[i]  = (_Float16)(X_in[(b0 + b) * Lc + t]);
    }
    if (tid < NBc * DECc) {
        const int b = tid >> 6, t = tid & 63;
        catob[tid]  = (unsigned char)cat_out[(b0 + b) * DECc + t];
        xo_lds[tid] = (_Float16)(cont_out[(b0 + b) * DECc + t] * w00);
    }
    for (int i = tid; i < CARD * EMBc; i += NTc) emb_lds[i] = (_Float16)emb_table[i];
    for (int i = tid; i < 6 * Hc; i += NTc) {
        const int o = i >> 7, k = i & 127;
        wh_lds[i] = (o == 0) ? Wm[k] : (o == 1) ? Ws[k] : Wv[(o - 2) * Hc + k];
    }
    if (tid == 0) { hb_lds[0] = bm[0]; hb_lds[1] = bs[0]; }
    if (tid < 4)  { hb_lds[2 + tid] = bv[tid]; }

    // ---- B-fragments: wave wv owns gates 64wv..64wv+63 (= cells 16wv..16wv+15 × 4 gates) ----
    half8 Bf[4][KT];
    float bias_s[4];
    #define LOAD_T(WIH, WHH, BB)                                               \
    {                                                                          \
        _Pragma("unroll")                                                      \
        for (int tile = 0; tile < 4; ++tile) {                                 \
            const int g   = 64 * wv + 16 * tile + col;                         \
            const int row = (g & 3) * Hc + (g >> 2);                           \
            _Pragma("unroll")                                                  \
            for (int kt = 0; kt < KT; ++kt) {                                  \
                half8 f;                                                       \
                _Pragma("unroll")                                              \
                for (int j = 0; j < 8; ++j) {                                  \
                    const int k = 32 * kt + 8 * q + j;                         \
                    float v = 0.0f;                                            \
                    if (k < INc)            v = WIH[row * INc + k];            \
                    else if (k < INc + Hc)  v = WHH[row * Hc + (k - INc)];     \
                    f[j] = (_Float16)v;                                        \
                }                                                              \
                Bf[tile][kt] = f;                                              \
            }                                                                  \
            bias_s[tile] = BB[row];                                            \
        }                                                                      \
    }

    LOAD_T(Wih_e, Whh_e, b_e);
    __syncthreads();

    // x(0) into buffer 0
    if (tid < INc * NBc) {
        _Float16 v;
        if (xk < EMBc)       v = emb_lds[(int)catb[xb * Lc] * EMBc + xk];
        else if (xk == EMBc) v = xs0[xb * Lc];
        else                 v = xs1[xb * Lc];
        z_lds[0][xb * ZS + xk] = v;
    }
    __syncthreads();

    int p = 0;
    float c_reg = 0.f;
    _Float16* scw = sc + wv * 256;
    const int gl = q * 16 + col;   // gate-local within wave

    // ===================== encoder: 1 barrier/step =====================
    for (int t = 0; t < Lc; ++t) {
        const _Float16* zr = &z_lds[p][0];
        _Float16*       zw = &z_lds[p ^ 1][0];

        // A-frags from z (batch = col&3)
        const _Float16* ap = zr + (col & 3) * ZS + 8 * q;
        half8 Az[KT];
        #pragma unroll
        for (int kt = 0; kt < KT; ++kt) Az[kt] = *(const half8*)(ap + 32 * kt);

        float4v acc[4];
        #pragma unroll
        for (int tile = 0; tile < 4; ++tile) {
            float4v a = {bias_s[tile], bias_s[tile], bias_s[tile], bias_s[tile]};
            #pragma unroll
            for (int kt = 0; kt < KT; ++kt)
                a = __builtin_amdgcn_mfma_f32_16x16x32_f16(Az[kt], Bf[tile][kt], a, 0, 0, 0);
            acc[tile] = a;
        }

        // intra-wave gate shuffle (no barrier): lane writes tile==q (rows replicated => valid)
        const float4v aw = (q == 0) ? acc[0] : (q == 1) ? acc[1] : (q == 2) ? acc[2] : acc[3];
        #pragma unroll
        for (int r = 0; r < 4; ++r) scw[r * 64 + gl] = (_Float16)aw[r];
        const half4 g4 = *(const half4*)(scw + ab * 64 + 4 * cl);   // i,f,g,o of (cell, ab)

        // LSTM cell update — one (cell,batch) per thread, optimal packing
        const float cn = sigm((float)g4[1]) * c_reg + sigm((float)g4[0]) * tanh_((float)g4[2]);
        c_reg = cn;
        zw[ab * ZS + INc + cell] = (_Float16)(sigm((float)g4[3]) * tanh_(cn));

        // x(t+1) (clamped: t=Lc-1 writes decoder-init x)
        if (tid < INc * NBc) {
            const int t1 = (t + 1 < Lc) ? t + 1 : Lc - 1;
            _Float16 v;
            if (xk < EMBc)       v = emb_lds[(int)catb[xb * Lc + t1] * EMBc + xk];
            else if (xk == EMBc) v = xs0[xb * Lc + t1];
            else                 v = xs1[xb * Lc + t1];
            zw[xb * ZS + xk] = v;
        }
        __syncthreads();
        p ^= 1;
    }

    // ===================== decoder =====================
    LOAD_T(Wih_d, Whh_d, b_d);
    const float bm0 = hb_lds[0], bs0 = hb_lds[1];

    for (int t = 0; t < DECc; ++t) {
        const _Float16* zr = &z_lds[p][0];
        _Float16*       zw = &z_lds[p ^ 1][0];

        const _Float16* ap = zr + (col & 3) * ZS + 8 * q;
        half8 Az[KT];
        #pragma unroll
        for (int kt = 0; kt < KT; ++kt) Az[kt] = *(const half8*)(ap + 32 * kt);

        float4v acc[4];
        #pragma unroll
        for (int tile = 0; tile < 4; ++tile) {
            float4v a = {bias_s[tile], bias_s[tile], bias_s[tile], bias_s[tile]};
            #pragma unroll
            for (int kt = 0; kt < KT; ++kt)
                a = __builtin_amdgcn_mfma_f32_16x16x32_f16(Az[kt], Bf[tile][kt], a, 0, 0, 0);
            acc[tile] = a;
        }

        const float4v aw = (q == 0) ? acc[0] : (q == 1) ? acc[1] : (q == 2) ? acc[2] : acc[3];
        #pragma unroll
        for (int r = 0; r < 4; ++r) scw[r * 64 + gl] = (_Float16)aw[r];
        const half4 g4 = *(const half4*)(scw + ab * 64 + 4 * cl);

        const float cn = sigm((float)g4[1]) * c_reg + sigm((float)g4[0]) * tanh_((float)g4[2]);
        c_reg = cn;
        const float hv = sigm((float)g4[3]) * tanh_(cn);
        zw[ab * ZS + INc + cell] = (_Float16)hv;
        h32_lds[ab * 132 + cell] = hv;

        // feats_out(t) -> x(t+1); slot 17 (mu) written by heads
        if (tid < INc * NBc && xk < INc - 1) {
            _Float16 v;
            if (xk < EMBc) v = emb_lds[(int)catob[xb * DECc + t] * EMBc + xk];
            else           v = xo_lds[xb * DECc + t];
            zw[xb * ZS + xk] = v;
        }
        __syncthreads();

        // heads
        if (tid < NBc * 8) {
            const int b = tid >> 3, o = tid & 7;
            if (o < 6) {
                float s = 0.0f;
                #pragma unroll 8
                for (int k = 0; k < Hc; ++k) s += wh_lds[o * Hc + k] * h32_lds[b * 132 + k];
                const int gb = b0 + b;
                if (o == 0) {
                    const float mu = s + bm0;
                    out[gb * DECc + t] = mu;
                    zw[b * ZS + (INc - 1)] = (_Float16)mu;   // mu feedback
                } else if (o == 1) {
                    out[65536 + gb * DECc + t] = softplus_(s + bs0);
                } else {
                    out[131072 + (gb * DECc + t) * 4 + (o - 2)] = s + hb_lds[2 + (o - 2)];
                }
            }
        }
        __syncthreads();
        p ^= 1;
    }
    #undef LOAD_T
}

extern "C" void kernel_launch(void* const* d_in, const int* in_sizes, int n_in,
                              void* d_out, int out_size, void* d_ws, size_t ws_size,
                              hipStream_t stream) {
    rnnar_kernel<<<1024 / NBc, NTc, 0, stream>>>(
        (const int*)d_in[0],   (const float*)d_in[1],  (const float*)d_in[2],
        (const int*)d_in[3],   (const float*)d_in[4],  (const float*)d_in[5],
        (const float*)d_in[6],
        (const float*)d_in[7], (const float*)d_in[8],  (const float*)d_in[9],
        (const float*)d_in[10],(const float*)d_in[11], (const float*)d_in[12],
        (const float*)d_in[13],(const float*)d_in[14],
        (const float*)d_in[15],(const float*)d_in[16],
        (const float*)d_in[17],(const float*)d_in[18],
        (float*)d_out);
}